// Round 7
// baseline (2795.426 us; speedup 1.0000x reference)
//
#include <hip/hip_runtime.h>

#define BB 4
#define NN 8192
#define MM 2048
#define KK 32
#define RROWS (BB*MM*KK)   // 262144 rows (b,m,k)

// Exact per-op squared distance: matches numpy/XLA (no FMA contraction, axis-order sum).
__device__ __forceinline__ float dist2(float ax,float ay,float az,float bx,float by,float bz){
    float dx=__fsub_rn(ax,bx), dy=__fsub_rn(ay,by), dz=__fsub_rn(az,bz);
    return __fadd_rn(__fadd_rn(__fmul_rn(dx,dx),__fmul_rn(dy,dy)),__fmul_rn(dz,dz));
}

// ---------------- FPS: one block per batch, 512 threads (8 waves), 16 pts/thread --------
// R6 post-mortem: VGPR=48 even with launch_bounds(512,2) -- the allocator SINKS the
// loop-invariant coord loads into the loop (re-fetch from L2 every step, ~2x step cost).
// Fix: asm-pin each loaded value ("+v") so it cannot be rematerialized and must stay
// in a VGPR for the kernel's lifetime. No math change -> identical selections.
__global__ __launch_bounds__(512, 2) void fps_kernel(const float* __restrict__ coords,
                                                     float* __restrict__ anchors)
{
    const int b = blockIdx.x, tid = threadIdx.x;
    const float* cb = coords + (size_t)b*NN*3;
    float* ab = anchors + (size_t)b*MM*3;
    float px[16],py[16],pz[16],dmin[16];
#pragma unroll
    for(int j=0;j<16;++j){
        int idx = j*512 + tid;
        px[j]=cb[idx*3+0]; py[j]=cb[idx*3+1]; pz[j]=cb[idx*3+2];
        // liveness pin: forbid rematerialization of these loads inside the step loop
        asm volatile("" : "+v"(px[j]), "+v"(py[j]), "+v"(pz[j]));
        dmin[j]=1e10f;
    }
    __shared__ unsigned long long slot[2][8];
    const int w = tid>>6;
    float lx=cb[0], ly=cb[1], lz=cb[2];
    if(tid==0){ ab[0]=lx; ab[1]=ly; ab[2]=lz; }
    for(int s=1;s<MM;++s){
        float bv=-1.f; int bi=0;
#pragma unroll
        for(int j=0;j<16;++j){
            float d = dist2(px[j],py[j],pz[j],lx,ly,lz);
            dmin[j]=fminf(dmin[j],d);                    // jnp.minimum
            if(dmin[j]>bv){ bv=dmin[j]; bi=j*512+tid; }  // strict > : lowest idx per thread
        }
        // pack: value bits (>=0, monotonic as uint) high, (NN-1-idx) low
        // -> u64 max == argmax with first-index tie-break
        unsigned long long p = ((unsigned long long)__float_as_uint(bv)<<32) | (unsigned)(NN-1-bi);
#pragma unroll
        for(int off=32;off;off>>=1){
            unsigned long long q = __shfl_xor(p, off);
            if(q>p) p=q;
        }
        const int par = s&1;
        if((tid&63)==0) slot[par][w]=p;
        __syncthreads();
        unsigned long long p0=slot[par][0], p1=slot[par][1], p2=slot[par][2], p3=slot[par][3];
        unsigned long long p4=slot[par][4], p5=slot[par][5], p6=slot[par][6], p7=slot[par][7];
        if(p1>p0) p0=p1;
        if(p3>p2) p2=p3;
        if(p5>p4) p4=p5;
        if(p7>p6) p6=p7;
        if(p2>p0) p0=p2;
        if(p6>p4) p4=p6;
        if(p4>p0) p0=p4;
        const int win = NN-1-(int)(unsigned)p0;
        lx=cb[win*3+0]; ly=cb[win*3+1]; lz=cb[win*3+2];  // uniform addr, L2-resident
        if(tid==0){ ab[s*3+0]=lx; ab[s*3+1]=ly; ab[s*3+2]=lz; }
    }
}

// ---------------- Ball query: 1 wave per anchor, ballot compaction ----------------
__global__ __launch_bounds__(256) void ballq_kernel(const float* __restrict__ coords,
                                                    const float* __restrict__ anchors,
                                                    int* __restrict__ nb)
{
    const int wid = threadIdx.x>>6, lane = threadIdx.x&63;
    const int a = blockIdx.x*4 + wid;            // 0..B*M-1
    const int b = a >> 11;                       // / MM
    const float* cb = coords + (size_t)b*NN*3;
    const float ax=anchors[a*3+0], ay=anchors[a*3+1], az=anchors[a*3+2];
    const float R2 = (float)(0.2*0.2);           // f64 product -> f32, matches JAX promotion
    int* out = nb + (size_t)a*KK;
    int cnt = 0, first = 0;
    for(int base=0; base<NN; base+=64){
        int i = base + lane;
        float d2 = dist2(ax,ay,az, cb[i*3+0],cb[i*3+1],cb[i*3+2]);
        bool in = d2 < R2;
        unsigned long long mask = __ballot(in);
        if(cnt==0 && mask) first = base + (int)__builtin_ctzll(mask);
        int pre = __popcll(mask & ((1ull<<lane)-1ull));
        if(in && (cnt+pre)<KK) out[cnt+pre] = i;
        cnt += __popcll(mask);
        if(cnt>=KK) break;
    }
    if(cnt<KK && lane>=cnt && lane<KK) out[lane] = first; // pad with first hit
}

// ---------------- Layer-0 stats pass (compute y0, discard, accumulate sum/sumsq) ----------------
__global__ __launch_bounds__(256) void l0_stats_kernel(
    const float* __restrict__ coords, const float* __restrict__ feats,
    const float* __restrict__ anchors, const int* __restrict__ nb,
    const float* __restrict__ W0, float* __restrict__ stats)
{
    const int r = blockIdx.x*256 + threadIdx.x;
    const int b = r>>16, mk = r&65535, m = mk>>5;
    const int p = nb[r];
    const float* pc = coords + ((size_t)b*NN + p)*3;
    const float* pa = anchors + ((size_t)b*MM + m)*3;
    const float* pf = feats + ((size_t)b*NN + p)*16;
    float x[19];
    x[0]=pc[0]-pa[0]; x[1]=pc[1]-pa[1]; x[2]=pc[2]-pa[2];
#pragma unroll
    for(int c=0;c<16;++c) x[3+c]=pf[c];
    __shared__ float lsum[4][64], lsq[4][64];
    const int lane = threadIdx.x&63, wid = threadIdx.x>>6;
    for(int o=0;o<64;++o){
        const float* w = W0 + o*19;
        float acc=0.f;
#pragma unroll
        for(int c=0;c<19;++c) acc = fmaf(x[c], w[c], acc);
        float s1=acc, s2=acc*acc;
#pragma unroll
        for(int off=32;off>0;off>>=1){ s1+=__shfl_xor(s1,off); s2+=__shfl_xor(s2,off); }
        if(lane==0){ lsum[wid][o]=s1; lsq[wid][o]=s2; }
    }
    __syncthreads();
    if(threadIdx.x<64){
        int o=threadIdx.x;
        atomicAdd(&stats[o],    lsum[0][o]+lsum[1][o]+lsum[2][o]+lsum[3][o]);
        atomicAdd(&stats[64+o], lsq[0][o]+lsq[1][o]+lsq[2][o]+lsq[3][o]);
    }
}

// ---------------- Finalize BN constants: s = g*rsqrt(var+eps), sh = b - mu*s ----------------
__global__ void fin_kernel(const float* __restrict__ acc, const float* __restrict__ g,
                           const float* __restrict__ bias, float* __restrict__ s,
                           float* __restrict__ sh, int C)
{
    int o = threadIdx.x; if(o>=C) return;
    const float R = (float)RROWS;
    float mu = acc[o]/R;
    float var = acc[C+o]/R - mu*mu;
    if(var<0.f) var=0.f;
    float sc = g[o] * (1.0f/sqrtf(var+1e-5f));
    s[o]=sc; sh[o]=bias[o]-mu*sc;
}

// ---------------- Layer-1: recompute y0, BN0+ReLU, y1 -> ws (transposed [o][r]), stats1 ----------------
__global__ __launch_bounds__(256) void l1_kernel(
    const float* __restrict__ coords, const float* __restrict__ feats,
    const float* __restrict__ anchors, const int* __restrict__ nb,
    const float* __restrict__ W0, const float* __restrict__ W1,
    const float* __restrict__ s0, const float* __restrict__ sh0,
    float* __restrict__ y1, float* __restrict__ stats)
{
    const int r = blockIdx.x*256 + threadIdx.x;
    const int b = r>>16, mk = r&65535, m = mk>>5;
    const int p = nb[r];
    const float* pc = coords + ((size_t)b*NN + p)*3;
    const float* pa = anchors + ((size_t)b*MM + m)*3;
    const float* pf = feats + ((size_t)b*NN + p)*16;
    float x[19];
    x[0]=pc[0]-pa[0]; x[1]=pc[1]-pa[1]; x[2]=pc[2]-pa[2];
#pragma unroll
    for(int c=0;c<16;++c) x[3+c]=pf[c];
    float x1[64];
#pragma unroll
    for(int o=0;o<64;++o){          // fully unrolled: x1 stays in registers (rule #20)
        const float* w = W0 + o*19;
        float acc=0.f;
#pragma unroll
        for(int c=0;c<19;++c) acc = fmaf(x[c], w[c], acc);
        x1[o] = fmaxf(fmaf(acc, s0[o], sh0[o]), 0.f);
    }
    __shared__ float lsum[4][64], lsq[4][64];
    const int lane = threadIdx.x&63, wid = threadIdx.x>>6;
    for(int o=0;o<64;++o){
        const float* w = W1 + o*64;
        float acc=0.f;
#pragma unroll
        for(int c=0;c<64;++c) acc = fmaf(x1[c], w[c], acc);
        y1[(size_t)o*RROWS + r] = acc;          // coalesced: lanes write consecutive r
        float s1=acc, s2=acc*acc;
#pragma unroll
        for(int off=32;off>0;off>>=1){ s1+=__shfl_xor(s1,off); s2+=__shfl_xor(s2,off); }
        if(lane==0){ lsum[wid][o]=s1; lsq[wid][o]=s2; }
    }
    __syncthreads();
    if(threadIdx.x<64){
        int o=threadIdx.x;
        atomicAdd(&stats[128+o], lsum[0][o]+lsum[1][o]+lsum[2][o]+lsum[3][o]);
        atomicAdd(&stats[192+o], lsq[0][o]+lsq[1][o]+lsq[2][o]+lsq[3][o]);
    }
}

// ---------------- Layer-2: BN1+ReLU, y2 (not stored): stats2 + per-(b,m,o) max/min over k ----------------
__global__ __launch_bounds__(256) void l2_kernel(
    const float* __restrict__ y1, const float* __restrict__ W2,
    const float* __restrict__ s1, const float* __restrict__ sh1,
    float* __restrict__ maxv, float* __restrict__ minv, float* __restrict__ stats)
{
    const int r = blockIdx.x*256 + threadIdx.x;
    float x1[64];
#pragma unroll
    for(int c=0;c<64;++c)                        // coalesced: lanes read consecutive r
        x1[c] = fmaxf(fmaf(y1[(size_t)c*RROWS + r], s1[c], sh1[c]), 0.f);
    __shared__ float lsum[4][128], lsq[4][128];
    const int lane = threadIdx.x&63, wid = threadIdx.x>>6;
    const size_t g = (size_t)(r>>5);   // (b,m) group: K=32 consecutive rows
    for(int o=0;o<128;++o){
        const float* w = W2 + o*64;
        float acc=0.f;
#pragma unroll
        for(int c=0;c<64;++c) acc = fmaf(x1[c], w[c], acc);
        float mx=acc, mn=acc;
#pragma unroll
        for(int off=16;off>0;off>>=1){ mx=fmaxf(mx,__shfl_xor(mx,off)); mn=fminf(mn,__shfl_xor(mn,off)); }
        float s1v=acc, s2v=acc*acc;
#pragma unroll
        for(int off=32;off>0;off>>=1){ s1v+=__shfl_xor(s1v,off); s2v+=__shfl_xor(s2v,off); }
        if((lane&31)==0){ maxv[g*128+o]=mx; minv[g*128+o]=mn; }
        if(lane==0){ lsum[wid][o]=s1v; lsq[wid][o]=s2v; }
    }
    __syncthreads();
    if(threadIdx.x<128){
        int o=threadIdx.x;
        atomicAdd(&stats[256+o], lsum[0][o]+lsum[1][o]+lsum[2][o]+lsum[3][o]);
        atomicAdd(&stats[384+o], lsq[0][o]+lsq[1][o]+lsq[2][o]+lsq[3][o]);
    }
}

// ---------------- Output: relu(s*pick+sh) where pick = max if s>=0 else min (exact commute) ----------------
__global__ __launch_bounds__(128) void out_kernel(
    const float* __restrict__ maxv, const float* __restrict__ minv,
    const float* __restrict__ s2, const float* __restrict__ sh2,
    float* __restrict__ agg)
{
    const int gg = blockIdx.x;     // 0..B*M-1
    const int o = threadIdx.x;     // 128
    float s = s2[o], sh = sh2[o];
    float pick = (s >= 0.f) ? maxv[(size_t)gg*128+o] : minv[(size_t)gg*128+o];
    float v = fmaxf(fmaf(pick, s, sh), 0.f);
    const int b = gg>>11, m = gg&2047;
    agg[((size_t)b*128 + o)*MM + m] = v;
}

extern "C" void kernel_launch(void* const* d_in, const int* in_sizes, int n_in,
                              void* d_out, int out_size, void* d_ws, size_t ws_size,
                              hipStream_t stream) {
    (void)in_sizes; (void)n_in; (void)out_size; (void)ws_size;
    const float* coords = (const float*)d_in[0];
    const float* feats  = (const float*)d_in[1];
    const float* W0 = (const float*)d_in[2];
    const float* g0 = (const float*)d_in[3];
    const float* b0 = (const float*)d_in[4];
    const float* W1 = (const float*)d_in[5];
    const float* g1 = (const float*)d_in[6];
    const float* b1 = (const float*)d_in[7];
    const float* W2 = (const float*)d_in[8];
    const float* g2 = (const float*)d_in[9];
    const float* b2 = (const float*)d_in[10];

    float* out = (float*)d_out;
    float* anchors = out;                      // [B,M,3]
    float* agg = out + (size_t)BB*MM*3;        // [B,128,M]

    // workspace layout (~73 MB)
    char* ws = (char*)d_ws;
    int*   nb    = (int*)ws;                                       // 262144 ints
    float* y1v   = (float*)(ws + 1048576);                         // 64 x RROWS f32 (transposed)
    float* maxv  = (float*)(ws + 1048576 + 67108864);              // B*M*128
    float* minv  = maxv + (size_t)BB*MM*128;
    float* stats = minv + (size_t)BB*MM*128;                       // 512 floats accum
    float* s0 = stats + 512; float* sh0 = s0 + 64;
    float* s1 = sh0 + 64;    float* sh1 = s1 + 64;
    float* s2 = sh1 + 64;    float* sh2 = s2 + 128;

    hipMemsetAsync(stats, 0, 512*sizeof(float), stream);
    fps_kernel  <<<BB, 512, 0, stream>>>(coords, anchors);
    ballq_kernel<<<BB*MM/4, 256, 0, stream>>>(coords, anchors, nb);
    l0_stats_kernel<<<RROWS/256, 256, 0, stream>>>(coords, feats, anchors, nb, W0, stats);
    fin_kernel  <<<1, 64, 0, stream>>>(stats, g0, b0, s0, sh0, 64);
    l1_kernel   <<<RROWS/256, 256, 0, stream>>>(coords, feats, anchors, nb, W0, W1, s0, sh0, y1v, stats);
    fin_kernel  <<<1, 64, 0, stream>>>(stats+128, g1, b1, s1, sh1, 64);
    l2_kernel   <<<RROWS/256, 256, 0, stream>>>(y1v, W2, s1, sh1, maxv, minv, stats);
    fin_kernel  <<<1, 128, 0, stream>>>(stats+256, g2, b2, s2, sh2, 128);
    out_kernel  <<<BB*MM, 128, 0, stream>>>(maxv, minv, s2, sh2, agg);
}

// Round 9
// 2714.150 us; speedup vs baseline: 1.0299x; 1.0299x over previous
//
#include <hip/hip_runtime.h>

#define BB 4
#define NN 8192
#define MM 2048
#define KK 32
#define RROWS (BB*MM*KK)   // 262144 rows (b,m,k)

// Exact per-op squared distance: matches numpy/XLA (no FMA contraction, axis-order sum).
__device__ __forceinline__ float dist2(float ax,float ay,float az,float bx,float by,float bz){
    float dx=__fsub_rn(ax,bx), dy=__fsub_rn(ay,by), dz=__fsub_rn(az,bz);
    return __fadd_rn(__fadd_rn(__fmul_rn(dx,dx),__fmul_rn(dy,dy)),__fmul_rn(dz,dz));
}

// ---------------- FPS v3: LDS-staged coords, one block/batch, 512 threads, 16 pts/thread
// R5-R7 post-mortem: hipcc refuses to keep 48 coord floats register-resident (VGPR=48
// regardless of launch_bounds/asm pins) and re-fetches them every one of 2047 steps.
// Fix: put coords in LDS under our control. Per-thread block of 16 pts = 48 dwords
// padded to 52 (208B, 16B-aligned) -> lane bank stride 52 % 32 spreads 8 banks/8 lanes
// (~2-way aliasing, free per m136). Only dmin[16] stays in registers.
__global__ __launch_bounds__(512, 2) void fps_kernel(const float* __restrict__ coords,
                                                     float* __restrict__ anchors)
{
    const int b = blockIdx.x, tid = threadIdx.x;
    const float* cb = coords + (size_t)b*NN*3;
    float* ab = anchors + (size_t)b*MM*3;
    __shared__ float c3[512*52];                 // 104 KB staged coords
    __shared__ unsigned long long slot[2][8];
#pragma unroll
    for(int j=0;j<16;++j){
        int p = tid*16 + j;
        c3[tid*52 + j*3 + 0] = cb[p*3+0];
        c3[tid*52 + j*3 + 1] = cb[p*3+1];
        c3[tid*52 + j*3 + 2] = cb[p*3+2];
    }
    float dmin[16];
#pragma unroll
    for(int j=0;j<16;++j) dmin[j]=1e10f;
    const int w = tid>>6;
    float lx=cb[0], ly=cb[1], lz=cb[2];
    if(tid==0){ ab[0]=lx; ab[1]=ly; ab[2]=lz; }
    __syncthreads();                             // staging complete
    for(int s=1;s<MM;++s){
        float bv=-1.f; int bi=0;
#pragma unroll
        for(int g=0;g<4;++g){                    // 4 pts per group: 12 dwords = 3x ds_read_b128
            const float4 fa = *reinterpret_cast<const float4*>(&c3[tid*52 + g*12 + 0]);
            const float4 fb = *reinterpret_cast<const float4*>(&c3[tid*52 + g*12 + 4]);
            const float4 fc = *reinterpret_cast<const float4*>(&c3[tid*52 + g*12 + 8]);
            // layout: [x0 y0 z0 x1][y1 z1 x2 y2][z2 x3 y3 z3]
            float d0 = dist2(fa.x,fa.y,fa.z,lx,ly,lz);
            float d1 = dist2(fa.w,fb.x,fb.y,lx,ly,lz);
            float d2 = dist2(fb.z,fb.w,fc.x,lx,ly,lz);
            float d3 = dist2(fc.y,fc.z,fc.w,lx,ly,lz);
            int j0=g*4;
            dmin[j0+0]=fminf(dmin[j0+0],d0);     // jnp.minimum
            dmin[j0+1]=fminf(dmin[j0+1],d1);
            dmin[j0+2]=fminf(dmin[j0+2],d2);
            dmin[j0+3]=fminf(dmin[j0+3],d3);
            // strict > : keeps lowest index per thread (ascending scan order)
            if(dmin[j0+0]>bv){ bv=dmin[j0+0]; bi=tid*16+j0+0; }
            if(dmin[j0+1]>bv){ bv=dmin[j0+1]; bi=tid*16+j0+1; }
            if(dmin[j0+2]>bv){ bv=dmin[j0+2]; bi=tid*16+j0+2; }
            if(dmin[j0+3]>bv){ bv=dmin[j0+3]; bi=tid*16+j0+3; }
        }
        // pack: value bits (>=0, monotonic as uint) high, (NN-1-idx) low
        // -> u64 max == argmax with first-index tie-break
        unsigned long long p = ((unsigned long long)__float_as_uint(bv)<<32) | (unsigned)(NN-1-bi);
#pragma unroll
        for(int off=32;off;off>>=1){
            unsigned long long q = __shfl_xor(p, off);
            if(q>p) p=q;
        }
        const int par = s&1;
        if((tid&63)==0) slot[par][w]=p;
        __syncthreads();
        unsigned long long p0=slot[par][0], p1=slot[par][1], p2=slot[par][2], p3=slot[par][3];
        unsigned long long p4=slot[par][4], p5=slot[par][5], p6=slot[par][6], p7=slot[par][7];
        if(p1>p0) p0=p1;
        if(p3>p2) p2=p3;
        if(p5>p4) p4=p5;
        if(p7>p6) p6=p7;
        if(p2>p0) p0=p2;
        if(p6>p4) p4=p6;
        if(p4>p0) p0=p4;
        const int win = NN-1-(int)(unsigned)p0;
        const int wbase = (win>>4)*52 + (win&15)*3;   // uniform LDS addr -> broadcast
        lx=c3[wbase+0]; ly=c3[wbase+1]; lz=c3[wbase+2];
        if(tid==0){ ab[s*3+0]=lx; ab[s*3+1]=ly; ab[s*3+2]=lz; }
    }
}

// ---------------- Ball query: 1 wave per anchor, ballot compaction ----------------
__global__ __launch_bounds__(256) void ballq_kernel(const float* __restrict__ coords,
                                                    const float* __restrict__ anchors,
                                                    int* __restrict__ nb)
{
    const int wid = threadIdx.x>>6, lane = threadIdx.x&63;
    const int a = blockIdx.x*4 + wid;            // 0..B*M-1
    const int b = a >> 11;                       // / MM
    const float* cb = coords + (size_t)b*NN*3;
    const float ax=anchors[a*3+0], ay=anchors[a*3+1], az=anchors[a*3+2];
    const float R2 = (float)(0.2*0.2);           // f64 product -> f32, matches JAX promotion
    int* out = nb + (size_t)a*KK;
    int cnt = 0, first = 0;
    for(int base=0; base<NN; base+=64){
        int i = base + lane;
        float d2 = dist2(ax,ay,az, cb[i*3+0],cb[i*3+1],cb[i*3+2]);
        bool in = d2 < R2;
        unsigned long long mask = __ballot(in);
        if(cnt==0 && mask) first = base + (int)__builtin_ctzll(mask);
        int pre = __popcll(mask & ((1ull<<lane)-1ull));
        if(in && (cnt+pre)<KK) out[cnt+pre] = i;
        cnt += __popcll(mask);
        if(cnt>=KK) break;
    }
    if(cnt<KK && lane>=cnt && lane<KK) out[lane] = first; // pad with first hit
}

// ---------------- Layer-0 stats pass (compute y0, discard, accumulate sum/sumsq) ----------------
__global__ __launch_bounds__(256) void l0_stats_kernel(
    const float* __restrict__ coords, const float* __restrict__ feats,
    const float* __restrict__ anchors, const int* __restrict__ nb,
    const float* __restrict__ W0, float* __restrict__ stats)
{
    const int r = blockIdx.x*256 + threadIdx.x;
    const int b = r>>16, mk = r&65535, m = mk>>5;
    const int p = nb[r];
    const float* pc = coords + ((size_t)b*NN + p)*3;
    const float* pa = anchors + ((size_t)b*MM + m)*3;
    const float* pf = feats + ((size_t)b*NN + p)*16;
    float x[19];
    x[0]=pc[0]-pa[0]; x[1]=pc[1]-pa[1]; x[2]=pc[2]-pa[2];
#pragma unroll
    for(int c=0;c<16;++c) x[3+c]=pf[c];
    __shared__ float lsum[4][64], lsq[4][64];
    const int lane = threadIdx.x&63, wid = threadIdx.x>>6;
    for(int o=0;o<64;++o){
        const float* w = W0 + o*19;
        float acc=0.f;
#pragma unroll
        for(int c=0;c<19;++c) acc = fmaf(x[c], w[c], acc);
        float s1=acc, s2=acc*acc;
#pragma unroll
        for(int off=32;off>0;off>>=1){ s1+=__shfl_xor(s1,off); s2+=__shfl_xor(s2,off); }
        if(lane==0){ lsum[wid][o]=s1; lsq[wid][o]=s2; }
    }
    __syncthreads();
    if(threadIdx.x<64){
        int o=threadIdx.x;
        atomicAdd(&stats[o],    lsum[0][o]+lsum[1][o]+lsum[2][o]+lsum[3][o]);
        atomicAdd(&stats[64+o], lsq[0][o]+lsq[1][o]+lsq[2][o]+lsq[3][o]);
    }
}

// ---------------- Finalize BN constants: s = g*rsqrt(var+eps), sh = b - mu*s ----------------
__global__ void fin_kernel(const float* __restrict__ acc, const float* __restrict__ g,
                           const float* __restrict__ bias, float* __restrict__ s,
                           float* __restrict__ sh, int C)
{
    int o = threadIdx.x; if(o>=C) return;
    const float R = (float)RROWS;
    float mu = acc[o]/R;
    float var = acc[C+o]/R - mu*mu;
    if(var<0.f) var=0.f;
    float sc = g[o] * (1.0f/sqrtf(var+1e-5f));
    s[o]=sc; sh[o]=bias[o]-mu*sc;
}

// ---------------- Layer-1: recompute y0, BN0+ReLU, y1 -> ws (transposed [o][r]), stats1 ----------------
__global__ __launch_bounds__(256) void l1_kernel(
    const float* __restrict__ coords, const float* __restrict__ feats,
    const float* __restrict__ anchors, const int* __restrict__ nb,
    const float* __restrict__ W0, const float* __restrict__ W1,
    const float* __restrict__ s0, const float* __restrict__ sh0,
    float* __restrict__ y1, float* __restrict__ stats)
{
    const int r = blockIdx.x*256 + threadIdx.x;
    const int b = r>>16, mk = r&65535, m = mk>>5;
    const int p = nb[r];
    const float* pc = coords + ((size_t)b*NN + p)*3;
    const float* pa = anchors + ((size_t)b*MM + m)*3;
    const float* pf = feats + ((size_t)b*NN + p)*16;
    float x[19];
    x[0]=pc[0]-pa[0]; x[1]=pc[1]-pa[1]; x[2]=pc[2]-pa[2];
#pragma unroll
    for(int c=0;c<16;++c) x[3+c]=pf[c];
    float x1[64];
#pragma unroll
    for(int o=0;o<64;++o){          // fully unrolled: x1 stays in registers (rule #20)
        const float* w = W0 + o*19;
        float acc=0.f;
#pragma unroll
        for(int c=0;c<19;++c) acc = fmaf(x[c], w[c], acc);
        x1[o] = fmaxf(fmaf(acc, s0[o], sh0[o]), 0.f);
    }
    __shared__ float lsum[4][64], lsq[4][64];
    const int lane = threadIdx.x&63, wid = threadIdx.x>>6;
    for(int o=0;o<64;++o){
        const float* w = W1 + o*64;
        float acc=0.f;
#pragma unroll
        for(int c=0;c<64;++c) acc = fmaf(x1[c], w[c], acc);
        y1[(size_t)o*RROWS + r] = acc;          // coalesced: lanes write consecutive r
        float s1=acc, s2=acc*acc;
#pragma unroll
        for(int off=32;off>0;off>>=1){ s1+=__shfl_xor(s1,off); s2+=__shfl_xor(s2,off); }
        if(lane==0){ lsum[wid][o]=s1; lsq[wid][o]=s2; }
    }
    __syncthreads();
    if(threadIdx.x<64){
        int o=threadIdx.x;
        atomicAdd(&stats[128+o], lsum[0][o]+lsum[1][o]+lsum[2][o]+lsum[3][o]);
        atomicAdd(&stats[192+o], lsq[0][o]+lsq[1][o]+lsq[2][o]+lsq[3][o]);
    }
}

// ---------------- Layer-2: BN1+ReLU, y2 (not stored): stats2 + per-(b,m,o) max/min over k ----------------
__global__ __launch_bounds__(256) void l2_kernel(
    const float* __restrict__ y1, const float* __restrict__ W2,
    const float* __restrict__ s1, const float* __restrict__ sh1,
    float* __restrict__ maxv, float* __restrict__ minv, float* __restrict__ stats)
{
    const int r = blockIdx.x*256 + threadIdx.x;
    float x1[64];
#pragma unroll
    for(int c=0;c<64;++c)                        // coalesced: lanes read consecutive r
        x1[c] = fmaxf(fmaf(y1[(size_t)c*RROWS + r], s1[c], sh1[c]), 0.f);
    __shared__ float lsum[4][128], lsq[4][128];
    const int lane = threadIdx.x&63, wid = threadIdx.x>>6;
    const size_t g = (size_t)(r>>5);   // (b,m) group: K=32 consecutive rows
    for(int o=0;o<128;++o){
        const float* w = W2 + o*64;
        float acc=0.f;
#pragma unroll
        for(int c=0;c<64;++c) acc = fmaf(x1[c], w[c], acc);
        float mx=acc, mn=acc;
#pragma unroll
        for(int off=16;off>0;off>>=1){ mx=fmaxf(mx,__shfl_xor(mx,off)); mn=fminf(mn,__shfl_xor(mn,off)); }
        float s1v=acc, s2v=acc*acc;
#pragma unroll
        for(int off=32;off>0;off>>=1){ s1v+=__shfl_xor(s1v,off); s2v+=__shfl_xor(s2v,off); }
        if((lane&31)==0){ maxv[g*128+o]=mx; minv[g*128+o]=mn; }
        if(lane==0){ lsum[wid][o]=s1v; lsq[wid][o]=s2v; }
    }
    __syncthreads();
    if(threadIdx.x<128){
        int o=threadIdx.x;
        atomicAdd(&stats[256+o], lsum[0][o]+lsum[1][o]+lsum[2][o]+lsum[3][o]);
        atomicAdd(&stats[384+o], lsq[0][o]+lsq[1][o]+lsq[2][o]+lsq[3][o]);
    }
}

// ---------------- Output: relu(s*pick+sh) where pick = max if s>=0 else min (exact commute) ----------------
__global__ __launch_bounds__(128) void out_kernel(
    const float* __restrict__ maxv, const float* __restrict__ minv,
    const float* __restrict__ s2, const float* __restrict__ sh2,
    float* __restrict__ agg)
{
    const int gg = blockIdx.x;     // 0..B*M-1
    const int o = threadIdx.x;     // 128
    float s = s2[o], sh = sh2[o];
    float pick = (s >= 0.f) ? maxv[(size_t)gg*128+o] : minv[(size_t)gg*128+o];
    float v = fmaxf(fmaf(pick, s, sh), 0.f);
    const int b = gg>>11, m = gg&2047;
    agg[((size_t)b*128 + o)*MM + m] = v;
}

extern "C" void kernel_launch(void* const* d_in, const int* in_sizes, int n_in,
                              void* d_out, int out_size, void* d_ws, size_t ws_size,
                              hipStream_t stream) {
    (void)in_sizes; (void)n_in; (void)out_size; (void)ws_size;
    const float* coords = (const float*)d_in[0];
    const float* feats  = (const float*)d_in[1];
    const float* W0 = (const float*)d_in[2];
    const float* g0 = (const float*)d_in[3];
    const float* b0 = (const float*)d_in[4];
    const float* W1 = (const float*)d_in[5];
    const float* g1 = (const float*)d_in[6];
    const float* b1 = (const float*)d_in[7];
    const float* W2 = (const float*)d_in[8];
    const float* g2 = (const float*)d_in[9];
    const float* b2 = (const float*)d_in[10];

    float* out = (float*)d_out;
    float* anchors = out;                      // [B,M,3]
    float* agg = out + (size_t)BB*MM*3;        // [B,128,M]

    // workspace layout (~73 MB)
    char* ws = (char*)d_ws;
    int*   nb    = (int*)ws;                                       // 262144 ints
    float* y1v   = (float*)(ws + 1048576);                         // 64 x RROWS f32 (transposed)
    float* maxv  = (float*)(ws + 1048576 + 67108864);              // B*M*128
    float* minv  = maxv + (size_t)BB*MM*128;
    float* stats = minv + (size_t)BB*MM*128;                       // 512 floats accum
    float* s0 = stats + 512; float* sh0 = s0 + 64;
    float* s1 = sh0 + 64;    float* sh1 = s1 + 64;
    float* s2 = sh1 + 64;    float* sh2 = s2 + 128;

    hipMemsetAsync(stats, 0, 512*sizeof(float), stream);
    fps_kernel  <<<BB, 512, 0, stream>>>(coords, anchors);
    ballq_kernel<<<BB*MM/4, 256, 0, stream>>>(coords, anchors, nb);
    l0_stats_kernel<<<RROWS/256, 256, 0, stream>>>(coords, feats, anchors, nb, W0, stats);
    fin_kernel  <<<1, 64, 0, stream>>>(stats, g0, b0, s0, sh0, 64);
    l1_kernel   <<<RROWS/256, 256, 0, stream>>>(coords, feats, anchors, nb, W0, W1, s0, sh0, y1v, stats);
    fin_kernel  <<<1, 64, 0, stream>>>(stats+128, g1, b1, s1, sh1, 64);
    l2_kernel   <<<RROWS/256, 256, 0, stream>>>(y1v, W2, s1, sh1, maxv, minv, stats);
    fin_kernel  <<<1, 128, 0, stream>>>(stats+256, g2, b2, s2, sh2, 128);
    out_kernel  <<<BB*MM, 128, 0, stream>>>(maxv, minv, s2, sh2, agg);
}